// Round 4
// baseline (279.981 us; speedup 1.0000x reference)
//
#include <hip/hip_runtime.h>
#include <math.h>

constexpr int CL = 256;
constexpr int CD = 768;
constexpr int CATT = 100;
constexpr int CH = 5;
constexpr int CDK = 20;

__device__ __forceinline__ void fma4(float4& a, float s, const float4& w) {
    a.x = fmaf(s, w.x, a.x);
    a.y = fmaf(s, w.y, a.y);
    a.z = fmaf(s, w.z, a.z);
    a.w = fmaf(s, w.w, a.w);
}

// 64x100-float tile prefetch (1600 float4 across 256 threads: 6 each + 7th for t<64)
struct WPref { float4 r[7]; };
__device__ __forceinline__ void pref_load(WPref& p, const float4* __restrict__ src, int t) {
#pragma unroll
    for (int m = 0; m < 6; ++m) p.r[m] = src[t + 256 * m];
    if (t < 64) p.r[6] = src[t + 1536];
}
__device__ __forceinline__ void pref_store(const WPref& p, float* dst, int t) {
    float4* d4 = (float4*)dst;
#pragma unroll
    for (int m = 0; m < 6; ++m) d4[t + 256 * m] = p.r[m];
    if (t < 64) d4[t + 1536] = p.r[6];
}

// ---------------------------------------------------------------------------
// k1: LN + g = xn@Wxx + b, q/k GEMMs, masked aspect pooling (atomics).
// 512 blocks x 16 rows. Double-buffered W/xn staging, ONE barrier per K-tile,
// contiguous (stride-100) LDS W => conflict-free staging stores.
// ---------------------------------------------------------------------------
__global__ __launch_bounds__(256) void k1_fused(
    const float* __restrict__ x, const float* __restrict__ ln_a,
    const float* __restrict__ ln_b, const float* __restrict__ Wxx_w,
    const float* __restrict__ Wxx_b, const float* __restrict__ q_w,
    const float* __restrict__ q_b, const float* __restrict__ k_w,
    const float* __restrict__ k_b, const float* __restrict__ amask,
    float* __restrict__ g, float* __restrict__ qt, float* __restrict__ ktb,
    float* __restrict__ aspect_raw)
{
    __shared__ float s_w[2][6400];     // W K-tile 64x100, contiguous; flat reuse for q/k (10000 fl)
    __shared__ float s_xn[2][16 * 68];
    __shared__ float s_gt[16 * 100];
    __shared__ float s_mean[16], s_rinv[16];

    const int t = threadIdx.x;
    const int r0 = blockIdx.x * 16;
    const int wid = t >> 6, lane = t & 63;

    // layernorm stats: wave wid owns rows wid*4..+3
    for (int rr = wid * 4; rr < wid * 4 + 4; ++rr) {
        const float* xr = x + (size_t)(r0 + rr) * CD;
        float xv[12];
        float s = 0.f;
#pragma unroll
        for (int m = 0; m < 12; ++m) { xv[m] = xr[lane + 64 * m]; s += xv[m]; }
#pragma unroll
        for (int o = 32; o; o >>= 1) s += __shfl_xor(s, o);
        float mean = s * (1.0f / 768.0f);
        float sq = 0.f;
#pragma unroll
        for (int m = 0; m < 12; ++m) { float d = xv[m] - mean; sq = fmaf(d, d, sq); }
#pragma unroll
        for (int o = 32; o; o >>= 1) sq += __shfl_xor(sq, o);
        if (lane == 0) {
            s_mean[rr] = mean;
            s_rinv[rr] = 1.0f / (sqrtf(sq * (1.0f / 767.0f)) + 1e-6f);
        }
    }

    const int cg = t % 25, rg = t / 25;
    const int c = cg * 4;
    const int xrow = t >> 4, xc4 = t & 15;
    const float* xrowp = x + (size_t)(r0 + xrow) * CD;

    // prefetch kt=0
    WPref wp;
    pref_load(wp, (const float4*)Wxx_w, t);
    float4 xp = *(const float4*)(xrowp + xc4 * 4);
    float4 la = *(const float4*)(ln_a + xc4 * 4);
    float4 lb = *(const float4*)(ln_b + xc4 * 4);

    __syncthreads();   // stats visible

    float4 acc0 = make_float4(0.f, 0.f, 0.f, 0.f);
    float4 acc1 = make_float4(0.f, 0.f, 0.f, 0.f);

    for (int kt = 0; kt < 12; ++kt) {
        float* wbuf = s_w[kt & 1];
        float* xbuf = s_xn[kt & 1];
        {   // store prefetched tile (xn normalized on the fly)
            float mean = s_mean[xrow], rinv = s_rinv[xrow];
            float4 v;
            v.x = fmaf(la.x, (xp.x - mean) * rinv, lb.x);
            v.y = fmaf(la.y, (xp.y - mean) * rinv, lb.y);
            v.z = fmaf(la.z, (xp.z - mean) * rinv, lb.z);
            v.w = fmaf(la.w, (xp.w - mean) * rinv, lb.w);
            *(float4*)&xbuf[xrow * 68 + xc4 * 4] = v;
            pref_store(wp, wbuf, t);
        }
        if (kt < 11) {
            pref_load(wp, (const float4*)Wxx_w + (size_t)(kt + 1) * 1600, t);
            int kb = (kt + 1) * 64 + xc4 * 4;
            xp = *(const float4*)(xrowp + kb);
            la = *(const float4*)(ln_a + kb);
            lb = *(const float4*)(ln_b + kb);
        }
        __syncthreads();   // buf(kt&1) ready; prior reads of it ended 2 iters ago
        if (t < 200) {
#pragma unroll 2
            for (int kk = 0; kk < 64; kk += 4) {
                float4 a0 = *(const float4*)&xbuf[(rg * 2 + 0) * 68 + kk];
                float4 a1 = *(const float4*)&xbuf[(rg * 2 + 1) * 68 + kk];
                float4 w0 = *(const float4*)&wbuf[(kk + 0) * 100 + c];
                float4 w1 = *(const float4*)&wbuf[(kk + 1) * 100 + c];
                float4 w2 = *(const float4*)&wbuf[(kk + 2) * 100 + c];
                float4 w3 = *(const float4*)&wbuf[(kk + 3) * 100 + c];
                fma4(acc0, a0.x, w0); fma4(acc0, a0.y, w1); fma4(acc0, a0.z, w2); fma4(acc0, a0.w, w3);
                fma4(acc1, a1.x, w0); fma4(acc1, a1.y, w1); fma4(acc1, a1.z, w2); fma4(acc1, a1.w, w3);
            }
        }
    }
    __syncthreads();   // all done with last tile before s_w reuse

    if (t < 200) {
        float4 bias = *(const float4*)&Wxx_b[c];
        float4 rv0, rv1;
        rv0.x = acc0.x + bias.x; rv0.y = acc0.y + bias.y; rv0.z = acc0.z + bias.z; rv0.w = acc0.w + bias.w;
        rv1.x = acc1.x + bias.x; rv1.y = acc1.y + bias.y; rv1.z = acc1.z + bias.z; rv1.w = acc1.w + bias.w;
        float4 rv[2] = { rv0, rv1 };
#pragma unroll
        for (int q = 0; q < 2; ++q) {
            int row = r0 + rg * 2 + q;
            *(float4*)&g[(size_t)row * CATT + c] = rv[q];
            *(float4*)&s_gt[(rg * 2 + q) * 100 + c] = rv[q];
            float m = amask[row];
            if (m != 0.f) {
                int b = row >> 8;
                atomicAdd(&aspect_raw[b * CATT + c + 0], m * rv[q].x);
                atomicAdd(&aspect_raw[b * CATT + c + 1], m * rv[q].y);
                atomicAdd(&aspect_raw[b * CATT + c + 2], m * rv[q].z);
                atomicAdd(&aspect_raw[b * CATT + c + 3], m * rv[q].w);
            }
        }
    }

    // q / k GEMMs: 100x100 W flat in s_w (contiguous, 10000 floats)
    float* swf = &s_w[0][0];
    for (int pass = 0; pass < 2; ++pass) {
        const float4* ws4 = (const float4*)(pass ? k_w : q_w);
        for (int i = t; i < 2500; i += 256) ((float4*)swf)[i] = ws4[i];
        __syncthreads();
        if (t < 200) {
            const float* bb = pass ? k_b : q_b;
            float* outp = pass ? ktb : qt;
            float4 b0 = make_float4(0.f, 0.f, 0.f, 0.f);
            float4 b1 = make_float4(0.f, 0.f, 0.f, 0.f);
#pragma unroll 2
            for (int k = 0; k < 100; k += 4) {
                float4 a0 = *(const float4*)&s_gt[(rg * 2 + 0) * 100 + k];
                float4 a1 = *(const float4*)&s_gt[(rg * 2 + 1) * 100 + k];
                float4 w0 = *(const float4*)&swf[(k + 0) * 100 + c];
                float4 w1 = *(const float4*)&swf[(k + 1) * 100 + c];
                float4 w2 = *(const float4*)&swf[(k + 2) * 100 + c];
                float4 w3 = *(const float4*)&swf[(k + 3) * 100 + c];
                fma4(b0, a0.x, w0); fma4(b0, a0.y, w1); fma4(b0, a0.z, w2); fma4(b0, a0.w, w3);
                fma4(b1, a1.x, w0); fma4(b1, a1.y, w1); fma4(b1, a1.z, w2); fma4(b1, a1.w, w3);
            }
            float4 bias = *(const float4*)&bb[c];
            b0.x += bias.x; b0.y += bias.y; b0.z += bias.z; b0.w += bias.w;
            b1.x += bias.x; b1.y += bias.y; b1.z += bias.z; b1.w += bias.w;
            const int h = c / CDK, d = c % CDK;
            float4 rv[2] = { b0, b1 };
#pragma unroll
            for (int q = 0; q < 2; ++q) {
                int row = r0 + rg * 2 + q;
                int bidx = row >> 8, l = row & 255;
                *(float4*)&outp[((size_t)(bidx * CH + h) * CL + l) * CDK + d] = rv[q];
            }
        }
        __syncthreads();
    }
}

// ---------------------------------------------------------------------------
// k45: inline asp + softmax (adjS in LDS, adjW->global) + GCN0 + rank-1 pieces
// 512 blocks (b, 16-row chunk). Double-buffered g staging, one barrier/tile.
// ---------------------------------------------------------------------------
__global__ __launch_bounds__(256) void k45_attn_gcn0(
    const float* __restrict__ qt, const float* __restrict__ ktb,
    const float* __restrict__ aspect_raw, const float* __restrict__ amask,
    const float* __restrict__ dense_w, const float* __restrict__ dense_b,
    const float* __restrict__ bias_m, const int* __restrict__ src_mask,
    const float* __restrict__ shortm, const float* __restrict__ Wx_w,
    const float* __restrict__ g, const float* __restrict__ W_w,
    const float* __restrict__ W_b, float* __restrict__ adjW,
    float* __restrict__ go1, float* __restrict__ t1, float* __restrict__ t2,
    float* __restrict__ gW2S)
{
    constexpr int ICH = 16;
    __shared__ float s_pool[16 * 260];  // adjS tile; later s_ax [0,1728) + s_go [1728,3392)
    __shared__ float s_w[2][6400];      // g tiles; flat reuse for W_w
    __shared__ float s_q[CH * 320];
    __shared__ float s_red[CH][64];
    __shared__ float s_was[5];
    __shared__ float s_aspb[20];
    __shared__ float s_w1[100], s_w2[100];
    __shared__ float s_g1row[16];

    const int b = blockIdx.x >> 4, ic = blockIdx.x & 15;
    const int i0 = ic * ICH;
    const int t = threadIdx.x, lane = t & 63, wid = t >> 6;
    const int j = t;

    // --- prologue: constants, asp (k2 folded in), q tiles for all heads
    if (t < 5) {
        float s = 0.f;
        for (int k2 = 0; k2 < 5; ++k2) s += Wx_w[t * 5 + k2];
        s_was[t] = s;
    }
    if (t < 100) {
        float a = 0.f, c2 = 0.f;
#pragma unroll
        for (int h = 0; h < 5; ++h) {
            a += Wx_w[(5 + t) * 5 + h];
            c2 += Wx_w[(105 + t) * 5 + h];
        }
        s_w1[t] = a; s_w2[t] = c2;
    }
    float wn = 0.f;
    if (t < 64) {
        float4 mv = ((const float4*)amask)[b * 64 + t];
        wn = mv.x + mv.y + mv.z + mv.w;
#pragma unroll
        for (int o = 32; o; o >>= 1) wn += __shfl_xor(wn, o);
    }
    if (t < 20) {
        float a = 0.f;
        for (int d = 0; d < CATT; ++d)
            a = fmaf(aspect_raw[b * CATT + d], dense_w[d * CDK + t], a);
        s_aspb[t] = a / wn + dense_b[t];
    }
    {
        const float* qbase = qt + (size_t)b * CH * CL * CDK + (size_t)i0 * CDK;
        for (int i = t; i < CH * 320; i += 256) {
            int h = i / 320, r = i % 320;
            s_q[i] = qbase[(size_t)h * CL * CDK + r];
        }
    }

    const bool masked = (src_mask[b * CL + j] == 0);
    const float bm = bias_m[0];
    const float rs20 = 0.223606797749978969f;

    float sm[ICH];
#pragma unroll
    for (int ii = 0; ii < ICH; ++ii)
        sm[ii] = shortm[(size_t)(b * CL + i0 + ii) * CL + j];

    float accS[ICH], accW[ICH];
#pragma unroll
    for (int ii = 0; ii < ICH; ++ii) { accS[ii] = 0.f; accW[ii] = 0.f; }

    __syncthreads();

    for (int h = 0; h < CH; ++h) {
        float4 kr[5];
        const float* kp = ktb + ((size_t)(b * CH + h) * CL + j) * CDK;
#pragma unroll
        for (int m = 0; m < 5; ++m) kr[m] = *(const float4*)(kp + 4 * m);
        const float was_h = s_was[h];
        float s = bm;
#pragma unroll
        for (int m = 0; m < 5; ++m) {
            s = fmaf(s_aspb[4 * m + 0], kr[m].x, s);
            s = fmaf(s_aspb[4 * m + 1], kr[m].y, s);
            s = fmaf(s_aspb[4 * m + 2], kr[m].z, s);
            s = fmaf(s_aspb[4 * m + 3], kr[m].w, s);
        }
        const float aspsc = tanhf(s);

        float pv[ICH];
#pragma unroll
        for (int ii = 0; ii < ICH; ++ii) {
            const float* qrow = &s_q[h * 320 + ii * CDK];
            float sc = 0.f;
#pragma unroll
            for (int m = 0; m < 5; ++m) {
                float4 q4 = *(const float4*)(qrow + 4 * m);
                sc = fmaf(q4.x, kr[m].x, sc);
                sc = fmaf(q4.y, kr[m].y, sc);
                sc = fmaf(q4.z, kr[m].z, sc);
                sc = fmaf(q4.w, kr[m].w, sc);
            }
            sc = fmaf(sc, rs20, aspsc) + sm[ii];
            float p = masked ? 0.f : __expf(sc);
            pv[ii] = p;
            float ssum = p;
#pragma unroll
            for (int o = 32; o; o >>= 1) ssum += __shfl_xor(ssum, o);
            if (lane == 0) s_red[h][ii * 4 + wid] = ssum;
        }
        __syncthreads();
#pragma unroll
        for (int ii = 0; ii < ICH; ++ii) {
            float tot = s_red[h][ii * 4 + 0] + s_red[h][ii * 4 + 1] +
                        s_red[h][ii * 4 + 2] + s_red[h][ii * 4 + 3];
            float pn = pv[ii] * __frcp_rn(tot);
            accS[ii] += pn;
            accW[ii] = fmaf(was_h, pn, accW[ii]);
        }
    }

#pragma unroll
    for (int ii = 0; ii < ICH; ++ii) {
        adjW[(size_t)(b * CL + i0 + ii) * CL + j] = accW[ii];
        s_pool[ii * 260 + j] = accS[ii];
    }

    // --- GEMM1: Ax = adjS_tile @ g (K=256, 4 double-buffered 64-tiles)
    const int cg = t % 25, rg = t / 25;
    const int c = cg * 4;
    WPref wp;
    pref_load(wp, (const float4*)g + (size_t)b * CL * 25, t);

    float4 acc0 = make_float4(0.f, 0.f, 0.f, 0.f);
    float4 acc1 = make_float4(0.f, 0.f, 0.f, 0.f);
    for (int jt = 0; jt < 4; ++jt) {
        float* wbuf = s_w[jt & 1];
        pref_store(wp, wbuf, t);
        if (jt < 3)
            pref_load(wp, (const float4*)g + (size_t)(b * CL + (jt + 1) * 64) * 25, t);
        __syncthreads();
        if (t < 200) {
#pragma unroll 2
            for (int kk = 0; kk < 64; kk += 4) {
                float4 a0 = *(const float4*)&s_pool[(rg * 2 + 0) * 260 + jt * 64 + kk];
                float4 a1 = *(const float4*)&s_pool[(rg * 2 + 1) * 260 + jt * 64 + kk];
                float4 w0 = *(const float4*)&wbuf[(kk + 0) * 100 + c];
                float4 w1 = *(const float4*)&wbuf[(kk + 1) * 100 + c];
                float4 w2 = *(const float4*)&wbuf[(kk + 2) * 100 + c];
                float4 w3 = *(const float4*)&wbuf[(kk + 3) * 100 + c];
                fma4(acc0, a0.x, w0); fma4(acc0, a0.y, w1); fma4(acc0, a0.z, w2); fma4(acc0, a0.w, w3);
                fma4(acc1, a1.x, w0); fma4(acc1, a1.y, w1); fma4(acc1, a1.z, w2); fma4(acc1, a1.w, w3);
            }
        }
    }
    __syncthreads();   // s_pool reads done -> safe to overlay s_ax

    float* s_ax = s_pool;            // 16 x 108
    if (t < 200) {
        float4 r;
        r.x = acc0.x * 0.2f; r.y = acc0.y * 0.2f; r.z = acc0.z * 0.2f; r.w = acc0.w * 0.2f;
        *(float4*)&s_ax[(rg * 2 + 0) * 108 + c] = r;
        r.x = acc1.x * 0.2f; r.y = acc1.y * 0.2f; r.z = acc1.z * 0.2f; r.w = acc1.w * 0.2f;
        *(float4*)&s_ax[(rg * 2 + 1) * 108 + c] = r;
    }
    float* swf = &s_w[0][0];
    {
        const float4* ws4 = (const float4*)W_w;
        for (int i = t; i < 2500; i += 256) ((float4*)swf)[i] = ws4[i];
    }
    __syncthreads();

    // --- GEMM2: go1 = relu(Ax @ W_w + W_b)
    float4 o0 = make_float4(0.f, 0.f, 0.f, 0.f);
    float4 o1 = make_float4(0.f, 0.f, 0.f, 0.f);
    if (t < 200) {
#pragma unroll 2
        for (int k = 0; k < 100; k += 4) {
            float4 a0 = *(const float4*)&s_ax[(rg * 2 + 0) * 108 + k];
            float4 a1 = *(const float4*)&s_ax[(rg * 2 + 1) * 108 + k];
            float4 w0 = *(const float4*)&swf[(k + 0) * 100 + c];
            float4 w1 = *(const float4*)&swf[(k + 1) * 100 + c];
            float4 w2 = *(const float4*)&swf[(k + 2) * 100 + c];
            float4 w3 = *(const float4*)&swf[(k + 3) * 100 + c];
            fma4(o0, a0.x, w0); fma4(o0, a0.y, w1); fma4(o0, a0.z, w2); fma4(o0, a0.w, w3);
            fma4(o1, a1.x, w0); fma4(o1, a1.y, w1); fma4(o1, a1.z, w2); fma4(o1, a1.w, w3);
        }
        float4 bias = *(const float4*)&W_b[c];
        o0.x = fmaxf(o0.x + bias.x, 0.f); o0.y = fmaxf(o0.y + bias.y, 0.f);
        o0.z = fmaxf(o0.z + bias.z, 0.f); o0.w = fmaxf(o0.w + bias.w, 0.f);
        o1.x = fmaxf(o1.x + bias.x, 0.f); o1.y = fmaxf(o1.y + bias.y, 0.f);
        o1.z = fmaxf(o1.z + bias.z, 0.f); o1.w = fmaxf(o1.w + bias.w, 0.f);
        *(float4*)&go1[(size_t)(b * CL + i0 + rg * 2 + 0) * CATT + c] = o0;
        *(float4*)&go1[(size_t)(b * CL + i0 + rg * 2 + 1) * CATT + c] = o1;
    }
    float* s_go = s_pool + 1728;     // 16 x 104 (disjoint from s_ax)
    if (t < 200) {
        *(float4*)&s_go[(rg * 2 + 0) * 104 + c] = o0;
        *(float4*)&s_go[(rg * 2 + 1) * 104 + c] = o1;
    }
    __syncthreads();

    // row dots: gw1 -> s_g1row, gw2 -> gW2S (8 threads / row)
    if (t < 128) {
        int r = t >> 3, seg = t & 7;
        int e0 = seg * 13, e1 = e0 + 13 < 100 ? e0 + 13 : 100;
        float a = 0.f, c2 = 0.f;
        for (int e = e0; e < e1; ++e) {
            float v = s_go[r * 104 + e];
            a = fmaf(v, s_w1[e], a);
            c2 = fmaf(v, s_w2[e], c2);
        }
        a += __shfl_xor(a, 1); a += __shfl_xor(a, 2); a += __shfl_xor(a, 4);
        c2 += __shfl_xor(c2, 1); c2 += __shfl_xor(c2, 2); c2 += __shfl_xor(c2, 4);
        if (seg == 0) {
            s_g1row[r] = a;
            gW2S[b * CL + i0 + r] = c2;
        }
    }
    __syncthreads();

    if (t < 100) {
        float a = 0.f, s2 = 0.f;
#pragma unroll
        for (int r = 0; r < 16; ++r) {
            float v = s_go[r * 104 + t];
            a = fmaf(s_g1row[r], v, a);
            s2 += v;
        }
        atomicAdd(&t1[b * CATT + t], a);
        atomicAdd(&t2[b * CATT + t], s2);
    }
}

// ---------------------------------------------------------------------------
// k7: GCN1 with rank-1 corrections; epilogue pools straight into out1_raw.
// Double-buffered go1 staging, one barrier per tile.
// ---------------------------------------------------------------------------
__global__ __launch_bounds__(256) void k7_gcn1(
    const float* __restrict__ adjW, const float* __restrict__ go1,
    const float* __restrict__ W_w, const float* __restrict__ W_b,
    const float* __restrict__ t1, const float* __restrict__ t2,
    const float* __restrict__ gW2S, const float* __restrict__ Wx_b,
    const float* __restrict__ amask, float* __restrict__ out1_raw)
{
    __shared__ float s_pool[16 * 260];  // adjW tile; later s_ax overlay
    __shared__ float s_w[2][6400];
    const int b = blockIdx.x >> 4, ic = blockIdx.x & 15;
    const int i0 = ic * 16;
    const int t = threadIdx.x;

    {
        const float4* asrc = (const float4*)adjW + (size_t)(b * CL + i0) * 64;
#pragma unroll
        for (int m = 0; m < 4; ++m) {
            int i = t + 256 * m;
            int row = i >> 6, c4 = i & 63;
            *(float4*)&s_pool[row * 260 + c4 * 4] = asrc[i];
        }
    }

    const int cg = t % 25, rg = t / 25;
    const int c = cg * 4;
    WPref wp;
    pref_load(wp, (const float4*)go1 + (size_t)b * CL * 25, t);

    float4 acc0 = make_float4(0.f, 0.f, 0.f, 0.f);
    float4 acc1 = make_float4(0.f, 0.f, 0.f, 0.f);
    for (int jt = 0; jt < 4; ++jt) {
        float* wbuf = s_w[jt & 1];
        pref_store(wp, wbuf, t);
        if (jt < 3)
            pref_load(wp, (const float4*)go1 + (size_t)(b * CL + (jt + 1) * 64) * 25, t);
        __syncthreads();
        if (t < 200) {
#pragma unroll 2
            for (int kk = 0; kk < 64; kk += 4) {
                float4 a0 = *(const float4*)&s_pool[(rg * 2 + 0) * 260 + jt * 64 + kk];
                float4 a1 = *(const float4*)&s_pool[(rg * 2 + 1) * 260 + jt * 64 + kk];
                float4 w0 = *(const float4*)&wbuf[(kk + 0) * 100 + c];
                float4 w1 = *(const float4*)&wbuf[(kk + 1) * 100 + c];
                float4 w2 = *(const float4*)&wbuf[(kk + 2) * 100 + c];
                float4 w3 = *(const float4*)&wbuf[(kk + 3) * 100 + c];
                fma4(acc0, a0.x, w0); fma4(acc0, a0.y, w1); fma4(acc0, a0.z, w2); fma4(acc0, a0.w, w3);
                fma4(acc1, a1.x, w0); fma4(acc1, a1.y, w1); fma4(acc1, a1.z, w2); fma4(acc1, a1.w, w3);
            }
        }
    }
    __syncthreads();

    float* s_ax = s_pool;
    if (t < 200) {
        float wxbs = Wx_b[0] + Wx_b[1] + Wx_b[2] + Wx_b[3] + Wx_b[4];
        float4 t1v = *(const float4*)&t1[b * CATT + c];
        float4 t2v = *(const float4*)&t2[b * CATT + c];
        float gw0 = gW2S[b * CL + i0 + rg * 2 + 0] + wxbs;
        float gw1 = gW2S[b * CL + i0 + rg * 2 + 1] + wxbs;
        float4 r;
        r.x = (acc0.x + t1v.x + gw0 * t2v.x) * 0.2f;
        r.y = (acc0.y + t1v.y + gw0 * t2v.y) * 0.2f;
        r.z = (acc0.z + t1v.z + gw0 * t2v.z) * 0.2f;
        r.w = (acc0.w + t1v.w + gw0 * t2v.w) * 0.2f;
        *(float4*)&s_ax[(rg * 2 + 0) * 108 + c] = r;
        r.x = (acc1.x + t1v.x + gw1 * t2v.x) * 0.2f;
        r.y = (acc1.y + t1v.y + gw1 * t2v.y) * 0.2f;
        r.z = (acc1.z + t1v.z + gw1 * t2v.z) * 0.2f;
        r.w = (acc1.w + t1v.w + gw1 * t2v.w) * 0.2f;
        *(float4*)&s_ax[(rg * 2 + 1) * 108 + c] = r;
    }
    float* swf = &s_w[0][0];
    {
        const float4* ws4 = (const float4*)W_w;
        for (int i = t; i < 2500; i += 256) ((float4*)swf)[i] = ws4[i];
    }
    __syncthreads();

    if (t < 200) {
        float4 o0 = make_float4(0.f, 0.f, 0.f, 0.f);
        float4 o1 = make_float4(0.f, 0.f, 0.f, 0.f);
#pragma unroll 2
        for (int k = 0; k < 100; k += 4) {
            float4 a0 = *(const float4*)&s_ax[(rg * 2 + 0) * 108 + k];
            float4 a1 = *(const float4*)&s_ax[(rg * 2 + 1) * 108 + k];
            float4 w0 = *(const float4*)&swf[(k + 0) * 100 + c];
            float4 w1 = *(const float4*)&swf[(k + 1) * 100 + c];
            float4 w2 = *(const float4*)&swf[(k + 2) * 100 + c];
            float4 w3 = *(const float4*)&swf[(k + 3) * 100 + c];
            fma4(o0, a0.x, w0); fma4(o0, a0.y, w1); fma4(o0, a0.z, w2); fma4(o0, a0.w, w3);
            fma4(o1, a1.x, w0); fma4(o1, a1.y, w1); fma4(o1, a1.z, w2); fma4(o1, a1.w, w3);
        }
        float4 bias = *(const float4*)&W_b[c];
        o0.x = fmaxf(o0.x + bias.x, 0.f); o0.y = fmaxf(o0.y + bias.y, 0.f);
        o0.z = fmaxf(o0.z + bias.z, 0.f); o0.w = fmaxf(o0.w + bias.w, 0.f);
        o1.x = fmaxf(o1.x + bias.x, 0.f); o1.y = fmaxf(o1.y + bias.y, 0.f);
        o1.z = fmaxf(o1.z + bias.z, 0.f); o1.w = fmaxf(o1.w + bias.w, 0.f);
        float4 ov[2] = { o0, o1 };
#pragma unroll
        for (int q = 0; q < 2; ++q) {
            int row = b * CL + i0 + rg * 2 + q;
            float m = amask[row];
            if (m != 0.f) {
                atomicAdd(&out1_raw[b * CATT + c + 0], m * ov[q].x);
                atomicAdd(&out1_raw[b * CATT + c + 1], m * ov[q].y);
                atomicAdd(&out1_raw[b * CATT + c + 2], m * ov[q].z);
                atomicAdd(&out1_raw[b * CATT + c + 3], m * ov[q].w);
            }
        }
    }
}

// ---------------------------------------------------------------------------
__global__ __launch_bounds__(64) void k8_small(
    const float* __restrict__ out1_raw, const float* __restrict__ amask,
    const float* __restrict__ clf_w, const float* __restrict__ clf_b,
    float* __restrict__ out)
{
    const int b = blockIdx.x, t = threadIdx.x;
    float4 mv = ((const float4*)amask)[b * 64 + t];
    float wn = mv.x + mv.y + mv.z + mv.w;
#pragma unroll
    for (int o = 32; o; o >>= 1) wn += __shfl_xor(wn, o);
    if (t < 3) {
        float rwn = 1.f / wn;
        float a = clf_b[t];
        for (int d = 0; d < CATT; ++d)
            a = fmaf(out1_raw[b * CATT + d] * rwn, clf_w[d * 3 + t], a);
        out[b * 3 + t] = a;
    }
}

// ---------------------------------------------------------------------------
extern "C" void kernel_launch(void* const* d_in, const int* in_sizes, int n_in,
                              void* d_out, int out_size, void* d_ws, size_t ws_size,
                              hipStream_t stream) {
    const float* seq     = (const float*)d_in[0];
    const int*   srcm    = (const int*)d_in[1];
    const float* amask   = (const float*)d_in[2];
    const float* shortm  = (const float*)d_in[3];
    const float* ln_a    = (const float*)d_in[4];
    const float* ln_b    = (const float*)d_in[5];
    const float* Wxx_w   = (const float*)d_in[6];
    const float* Wxx_b   = (const float*)d_in[7];
    const float* q_w     = (const float*)d_in[8];
    const float* q_b     = (const float*)d_in[9];
    const float* k_w     = (const float*)d_in[10];
    const float* k_b     = (const float*)d_in[11];
    const float* dense_w = (const float*)d_in[12];
    const float* dense_b = (const float*)d_in[13];
    const float* bias_m  = (const float*)d_in[14];
    const float* W_w     = (const float*)d_in[15];
    const float* W_b     = (const float*)d_in[16];
    const float* Wx_w    = (const float*)d_in[17];
    const float* Wx_b    = (const float*)d_in[18];
    const float* clf_w   = (const float*)d_in[19];
    const float* clf_b   = (const float*)d_in[20];
    float* out = (float*)d_out;

    float* ws         = (float*)d_ws;
    float* g          = ws;
    float* qt         = g + 819200;
    float* ktb        = qt + 819200;
    float* go1        = ktb + 819200;
    float* adjW       = go1 + 819200;
    float* aspect_raw = adjW + 2097152;
    float* t1         = aspect_raw + 3200;
    float* t2         = t1 + 3200;
    float* out1_raw   = t2 + 3200;
    float* gW2S       = out1_raw + 3200;

    hipMemsetAsync(aspect_raw, 0, 4 * 3200 * sizeof(float), stream);
    hipLaunchKernelGGL(k1_fused, dim3(512), dim3(256), 0, stream, seq, ln_a, ln_b,
                       Wxx_w, Wxx_b, q_w, q_b, k_w, k_b, amask, g, qt, ktb, aspect_raw);
    hipLaunchKernelGGL(k45_attn_gcn0, dim3(512), dim3(256), 0, stream,
                       qt, ktb, aspect_raw, amask, dense_w, dense_b, bias_m, srcm,
                       shortm, Wx_w, g, W_w, W_b, adjW, go1, t1, t2, gW2S);
    hipLaunchKernelGGL(k7_gcn1, dim3(512), dim3(256), 0, stream,
                       adjW, go1, W_w, W_b, t1, t2, gW2S, Wx_b, amask, out1_raw);
    hipLaunchKernelGGL(k8_small, dim3(32), dim3(64), 0, stream,
                       out1_raw, amask, clf_w, clf_b, out);
}

// Round 5
// 241.762 us; speedup vs baseline: 1.1581x; 1.1581x over previous
//
#include <hip/hip_runtime.h>
#include <math.h>

constexpr int CL = 256;
constexpr int CD = 768;
constexpr int CATT = 100;
constexpr int CH = 5;
constexpr int CDK = 20;

__device__ __forceinline__ void fma4(float4& a, float s, const float4& w) {
    a.x = fmaf(s, w.x, a.x);
    a.y = fmaf(s, w.y, a.y);
    a.z = fmaf(s, w.z, a.z);
    a.w = fmaf(s, w.w, a.w);
}

// ---------------------------------------------------------------------------
// k1: LN + g = xn@Wxx + b, q/k GEMMs, masked aspect pooling (atomics).
// 512 blocks x 16 rows. K-tiles of 32 (main) / 20 (q,k), double-buffered,
// ONE barrier per tile. Staging via 3-4 transient float4 regs (r4's 28-reg
// WPref spilled: 55MB scratch writes). ~43KB LDS -> 3 blocks/CU.
// ---------------------------------------------------------------------------
__global__ __launch_bounds__(256, 3) void k1_fused(
    const float* __restrict__ x, const float* __restrict__ ln_a,
    const float* __restrict__ ln_b, const float* __restrict__ Wxx_w,
    const float* __restrict__ Wxx_b, const float* __restrict__ q_w,
    const float* __restrict__ q_b, const float* __restrict__ k_w,
    const float* __restrict__ k_b, const float* __restrict__ amask,
    float* __restrict__ g, float* __restrict__ qt, float* __restrict__ ktb,
    float* __restrict__ aspect_raw)
{
    __shared__ float s_w[2][3200];      // 32x100 W tile (>= 20x100 for q/k)
    __shared__ float s_xn[2][16 * 36];  // 16 x 32 xn tile, stride 36
    __shared__ float s_gt[16 * 100];
    __shared__ float s_ln[1536];        // ln_a | ln_b
    __shared__ float s_mean[16], s_rinv[16];

    const int t = threadIdx.x;
    const int r0 = blockIdx.x * 16;
    const int wid = t >> 6, lane = t & 63;

    if (t < 192) {
        ((float4*)s_ln)[t] = ((const float4*)ln_a)[t];
        ((float4*)(s_ln + 768))[t] = ((const float4*)ln_b)[t];
    }

    // layernorm stats: wave wid owns rows wid*4..+3
    for (int rr = wid * 4; rr < wid * 4 + 4; ++rr) {
        const float* xr = x + (size_t)(r0 + rr) * CD;
        float xv[12];
        float s = 0.f;
#pragma unroll
        for (int m = 0; m < 12; ++m) { xv[m] = xr[lane + 64 * m]; s += xv[m]; }
#pragma unroll
        for (int o = 32; o; o >>= 1) s += __shfl_xor(s, o);
        float mean = s * (1.0f / 768.0f);
        float sq = 0.f;
#pragma unroll
        for (int m = 0; m < 12; ++m) { float d = xv[m] - mean; sq = fmaf(d, d, sq); }
#pragma unroll
        for (int o = 32; o; o >>= 1) sq += __shfl_xor(sq, o);
        if (lane == 0) {
            s_mean[rr] = mean;
            s_rinv[rr] = 1.0f / (sqrtf(sq * (1.0f / 767.0f)) + 1e-6f);
        }
    }

    // prefetch tile 0 (W 32x100 = 800 float4; x 16x32 = 2 floats/thread)
    const float4* wsrc = (const float4*)Wxx_w;
    float4 w0 = wsrc[t], w1 = wsrc[t + 256], w2 = wsrc[t + 512], w3;
    if (t < 32) w3 = wsrc[t + 768];
    const int rA = t >> 5, cA = t & 31;
    float xa = x[(size_t)(r0 + rA) * CD + cA];
    float xb = x[(size_t)(r0 + rA + 8) * CD + cA];

    __syncthreads();   // s_ln + stats visible

    {
        float4* d4 = (float4*)s_w[0];
        d4[t] = w0; d4[t + 256] = w1; d4[t + 512] = w2;
        if (t < 32) d4[t + 768] = w3;
        float la = s_ln[cA], lbv = s_ln[768 + cA];
        s_xn[0][rA * 36 + cA] = fmaf(la, (xa - s_mean[rA]) * s_rinv[rA], lbv);
        s_xn[0][(rA + 8) * 36 + cA] = fmaf(la, (xb - s_mean[rA + 8]) * s_rinv[rA + 8], lbv);
    }
    __syncthreads();

    const int cg = t % 25, rg = t / 25;
    const int c = cg * 4;
    float4 acc0 = make_float4(0.f, 0.f, 0.f, 0.f);
    float4 acc1 = make_float4(0.f, 0.f, 0.f, 0.f);

    for (int kt = 0; kt < 24; ++kt) {
        if (kt < 23) {   // issue next-tile loads; they fly during compute
            const float4* ws = wsrc + (size_t)(kt + 1) * 800;
            w0 = ws[t]; w1 = ws[t + 256]; w2 = ws[t + 512];
            if (t < 32) w3 = ws[t + 768];
            int gc = (kt + 1) * 32 + cA;
            xa = x[(size_t)(r0 + rA) * CD + gc];
            xb = x[(size_t)(r0 + rA + 8) * CD + gc];
        }
        if (t < 200) {
            const float* wb = s_w[kt & 1];
            const float* xbuf = s_xn[kt & 1];
#pragma unroll 2
            for (int kk = 0; kk < 32; kk += 4) {
                float4 a0 = *(const float4*)&xbuf[(rg * 2 + 0) * 36 + kk];
                float4 a1 = *(const float4*)&xbuf[(rg * 2 + 1) * 36 + kk];
                float4 v0 = *(const float4*)&wb[(kk + 0) * 100 + c];
                float4 v1 = *(const float4*)&wb[(kk + 1) * 100 + c];
                float4 v2 = *(const float4*)&wb[(kk + 2) * 100 + c];
                float4 v3 = *(const float4*)&wb[(kk + 3) * 100 + c];
                fma4(acc0, a0.x, v0); fma4(acc0, a0.y, v1); fma4(acc0, a0.z, v2); fma4(acc0, a0.w, v3);
                fma4(acc1, a1.x, v0); fma4(acc1, a1.y, v1); fma4(acc1, a1.z, v2); fma4(acc1, a1.w, v3);
            }
        }
        if (kt < 23) {   // store next tile to the other buffer
            float4* d4 = (float4*)s_w[(kt + 1) & 1];
            d4[t] = w0; d4[t + 256] = w1; d4[t + 512] = w2;
            if (t < 32) d4[t + 768] = w3;
            int gc = (kt + 1) * 32 + cA;
            float la = s_ln[gc], lbv = s_ln[768 + gc];
            float* xd = s_xn[(kt + 1) & 1];
            xd[rA * 36 + cA] = fmaf(la, (xa - s_mean[rA]) * s_rinv[rA], lbv);
            xd[(rA + 8) * 36 + cA] = fmaf(la, (xb - s_mean[rA + 8]) * s_rinv[rA + 8], lbv);
        }
        __syncthreads();
    }

    if (t < 200) {
        float4 bias = *(const float4*)&Wxx_b[c];
        float4 rv0, rv1;
        rv0.x = acc0.x + bias.x; rv0.y = acc0.y + bias.y; rv0.z = acc0.z + bias.z; rv0.w = acc0.w + bias.w;
        rv1.x = acc1.x + bias.x; rv1.y = acc1.y + bias.y; rv1.z = acc1.z + bias.z; rv1.w = acc1.w + bias.w;
        float4 rv[2] = { rv0, rv1 };
#pragma unroll
        for (int q = 0; q < 2; ++q) {
            int row = r0 + rg * 2 + q;
            *(float4*)&g[(size_t)row * CATT + c] = rv[q];
            *(float4*)&s_gt[(rg * 2 + q) * 100 + c] = rv[q];
            float m = amask[row];
            if (m != 0.f) {
                int b = row >> 8;
                atomicAdd(&aspect_raw[b * CATT + c + 0], m * rv[q].x);
                atomicAdd(&aspect_raw[b * CATT + c + 1], m * rv[q].y);
                atomicAdd(&aspect_raw[b * CATT + c + 2], m * rv[q].z);
                atomicAdd(&aspect_raw[b * CATT + c + 3], m * rv[q].w);
            }
        }
    }

    // q/k phase: 10 pipelined 20x100 tiles (0-4: q_w, 5-9: k_w), 500 f4 each
    const float4* qw4 = (const float4*)q_w;
    const float4* kw4 = (const float4*)k_w;
    float4 sA = qw4[t], sB;
    if (t < 244) sB = qw4[t + 256];
    __syncthreads();   // s_gt visible; main-loop LDS traffic done
    {
        float4* d4 = (float4*)s_w[0];
        d4[t] = sA; if (t < 244) d4[t + 256] = sB;
    }
    __syncthreads();

    float4 p0 = make_float4(0.f, 0.f, 0.f, 0.f);
    float4 p1 = make_float4(0.f, 0.f, 0.f, 0.f);
    for (int tau = 0; tau < 10; ++tau) {
        if (tau < 9) {
            const float4* src = (tau + 1 < 5) ? qw4 + (size_t)(tau + 1) * 500
                                              : kw4 + (size_t)(tau - 4) * 500;
            sA = src[t]; if (t < 244) sB = src[t + 256];
        }
        if (t < 200) {
            const float* wb = s_w[tau & 1];
            const int kb = (tau % 5) * 20;
#pragma unroll 2
            for (int kk = 0; kk < 20; kk += 4) {
                float4 a0 = *(const float4*)&s_gt[(rg * 2 + 0) * 100 + kb + kk];
                float4 a1 = *(const float4*)&s_gt[(rg * 2 + 1) * 100 + kb + kk];
                float4 v0 = *(const float4*)&wb[(kk + 0) * 100 + c];
                float4 v1 = *(const float4*)&wb[(kk + 1) * 100 + c];
                float4 v2 = *(const float4*)&wb[(kk + 2) * 100 + c];
                float4 v3 = *(const float4*)&wb[(kk + 3) * 100 + c];
                fma4(p0, a0.x, v0); fma4(p0, a0.y, v1); fma4(p0, a0.z, v2); fma4(p0, a0.w, v3);
                fma4(p1, a1.x, v0); fma4(p1, a1.y, v1); fma4(p1, a1.z, v2); fma4(p1, a1.w, v3);
            }
            if (tau == 4 || tau == 9) {
                const float* bb = (tau == 4) ? q_b : k_b;
                float* outp = (tau == 4) ? qt : ktb;
                float4 bias = *(const float4*)&bb[c];
                p0.x += bias.x; p0.y += bias.y; p0.z += bias.z; p0.w += bias.w;
                p1.x += bias.x; p1.y += bias.y; p1.z += bias.z; p1.w += bias.w;
                const int h = c / CDK, d = c % CDK;
                float4 rv[2] = { p0, p1 };
#pragma unroll
                for (int q = 0; q < 2; ++q) {
                    int row = r0 + rg * 2 + q;
                    int bidx = row >> 8, l = row & 255;
                    *(float4*)&outp[((size_t)(bidx * CH + h) * CL + l) * CDK + d] = rv[q];
                }
                p0 = make_float4(0.f, 0.f, 0.f, 0.f);
                p1 = make_float4(0.f, 0.f, 0.f, 0.f);
            }
        }
        if (tau < 9) {
            float4* d4 = (float4*)s_w[(tau + 1) & 1];
            d4[t] = sA; if (t < 244) d4[t + 256] = sB;
        }
        __syncthreads();
    }
}

// ---------------------------------------------------------------------------
// k45: inline asp + softmax (adjS in LDS, adjW->global) + GCN0 + rank-1.
// GEMM1: 8 pipelined 32x100 g tiles; GEMM2: 5 pipelined 20x100 W_w tiles.
// ---------------------------------------------------------------------------
__global__ __launch_bounds__(256, 3) void k45_attn_gcn0(
    const float* __restrict__ qt, const float* __restrict__ ktb,
    const float* __restrict__ aspect_raw, const float* __restrict__ amask,
    const float* __restrict__ dense_w, const float* __restrict__ dense_b,
    const float* __restrict__ bias_m, const int* __restrict__ src_mask,
    const float* __restrict__ shortm, const float* __restrict__ Wx_w,
    const float* __restrict__ g, const float* __restrict__ W_w,
    const float* __restrict__ W_b, float* __restrict__ adjW,
    float* __restrict__ go1, float* __restrict__ t1, float* __restrict__ t2,
    float* __restrict__ gW2S)
{
    constexpr int ICH = 16;
    __shared__ float s_pool[16 * 260];  // adjS tile; later s_ax [0,1728) + s_go [1728,3392)
    __shared__ float s_w[2][3200];      // g / W_w tiles
    __shared__ float s_q[CH * 320];
    __shared__ float s_red[CH][64];
    __shared__ float s_was[5];
    __shared__ float s_aspb[20];
    __shared__ float s_w1[100], s_w2[100];
    __shared__ float s_g1row[16];

    const int b = blockIdx.x >> 4, ic = blockIdx.x & 15;
    const int i0 = ic * ICH;
    const int t = threadIdx.x, lane = t & 63, wid = t >> 6;
    const int j = t;

    if (t < 5) {
        float s = 0.f;
        for (int k2 = 0; k2 < 5; ++k2) s += Wx_w[t * 5 + k2];
        s_was[t] = s;
    }
    if (t < 100) {
        float a = 0.f, c2 = 0.f;
#pragma unroll
        for (int h = 0; h < 5; ++h) {
            a += Wx_w[(5 + t) * 5 + h];
            c2 += Wx_w[(105 + t) * 5 + h];
        }
        s_w1[t] = a; s_w2[t] = c2;
    }
    float wn = 0.f;
    if (t < 64) {
        float4 mv = ((const float4*)amask)[b * 64 + t];
        wn = mv.x + mv.y + mv.z + mv.w;
#pragma unroll
        for (int o = 32; o; o >>= 1) wn += __shfl_xor(wn, o);
    }
    if (t < 20) {
        float a = 0.f;
        for (int d = 0; d < CATT; ++d)
            a = fmaf(aspect_raw[b * CATT + d], dense_w[d * CDK + t], a);
        s_aspb[t] = a / wn + dense_b[t];
    }
    {
        const float* qbase = qt + (size_t)b * CH * CL * CDK + (size_t)i0 * CDK;
        for (int i = t; i < CH * 320; i += 256) {
            int h = i / 320, r = i % 320;
            s_q[i] = qbase[(size_t)h * CL * CDK + r];
        }
    }

    const bool masked = (src_mask[b * CL + j] == 0);
    const float bm = bias_m[0];
    const float rs20 = 0.223606797749978969f;

    float sm[ICH];
#pragma unroll
    for (int ii = 0; ii < ICH; ++ii)
        sm[ii] = shortm[(size_t)(b * CL + i0 + ii) * CL + j];

    float accS[ICH], accW[ICH];
#pragma unroll
    for (int ii = 0; ii < ICH; ++ii) { accS[ii] = 0.f; accW[ii] = 0.f; }

    __syncthreads();

    for (int h = 0; h < CH; ++h) {
        float4 kr[5];
        const float* kp = ktb + ((size_t)(b * CH + h) * CL + j) * CDK;
#pragma unroll
        for (int m = 0; m < 5; ++m) kr[m] = *(const float4*)(kp + 4 * m);
        const float was_h = s_was[h];
        float s = bm;
#pragma unroll
        for (int m = 0; m < 5; ++m) {
            s = fmaf(s_aspb[4 * m + 0], kr[m].x, s);
            s = fmaf(s_aspb[4 * m + 1], kr[m].y, s);
            s = fmaf(s_aspb[4 * m + 2], kr[m].z, s);
            s = fmaf(s_aspb[4 * m + 3], kr[m].w, s);
        }
        const float aspsc = tanhf(s);

        float pv[ICH];
#pragma unroll
        for (int ii = 0; ii < ICH; ++ii) {
            const float* qrow = &s_q[h * 320 + ii * CDK];
            float sc = 0.f;
#pragma unroll
            for (int m = 0; m < 5; ++m) {
                float4 q4 = *(const float4*)(qrow + 4 * m);
                sc = fmaf(q4.x, kr[m].x, sc);
                sc = fmaf(q4.y, kr[m].y, sc);
                sc = fmaf(q4.z, kr[m].z, sc);
                sc = fmaf(q4.w, kr[m].w, sc);
            }
            sc = fmaf(sc, rs20, aspsc) + sm[ii];
            float p = masked ? 0.f : __expf(sc);
            pv[ii] = p;
            float ssum = p;
#pragma unroll
            for (int o = 32; o; o >>= 1) ssum += __shfl_xor(ssum, o);
            if (lane == 0) s_red[h][ii * 4 + wid] = ssum;
        }
        __syncthreads();
#pragma unroll
        for (int ii = 0; ii < ICH; ++ii) {
            float tot = s_red[h][ii * 4 + 0] + s_red[h][ii * 4 + 1] +
                        s_red[h][ii * 4 + 2] + s_red[h][ii * 4 + 3];
            float pn = pv[ii] * __frcp_rn(tot);
            accS[ii] += pn;
            accW[ii] = fmaf(was_h, pn, accW[ii]);
        }
    }

#pragma unroll
    for (int ii = 0; ii < ICH; ++ii) {
        adjW[(size_t)(b * CL + i0 + ii) * CL + j] = accW[ii];
        s_pool[ii * 260 + j] = accS[ii];
    }

    // --- GEMM1: Ax = adjS_tile @ g (K=256, 8 pipelined 32-row tiles)
    const int cg = t % 25, rg = t / 25;
    const int c = cg * 4;
    const float4* g4 = (const float4*)g + (size_t)b * 6400;
    float4 sA = g4[t], sB = g4[t + 256], sC = g4[t + 512], sD;
    if (t < 32) sD = g4[t + 768];
    {
        float4* d4 = (float4*)s_w[0];
        d4[t] = sA; d4[t + 256] = sB; d4[t + 512] = sC;
        if (t < 32) d4[t + 768] = sD;
    }
    __syncthreads();   // s_pool + tile0 visible

    float4 acc0 = make_float4(0.f, 0.f, 0.f, 0.f);
    float4 acc1 = make_float4(0.f, 0.f, 0.f, 0.f);
    for (int jt = 0; jt < 8; ++jt) {
        if (jt < 7) {
            const float4* src = g4 + (size_t)(jt + 1) * 800;
            sA = src[t]; sB = src[t + 256]; sC = src[t + 512];
            if (t < 32) sD = src[t + 768];
        }
        if (t < 200) {
            const float* wb = s_w[jt & 1];
#pragma unroll 2
            for (int kk = 0; kk < 32; kk += 4) {
                float4 a0 = *(const float4*)&s_pool[(rg * 2 + 0) * 260 + jt * 32 + kk];
                float4 a1 = *(const float4*)&s_pool[(rg * 2 + 1) * 260 + jt * 32 + kk];
                float4 v0 = *(const float4*)&wb[(kk + 0) * 100 + c];
                float4 v1 = *(const float4*)&wb[(kk + 1) * 100 + c];
                float4 v2 = *(const float4*)&wb[(kk + 2) * 100 + c];
                float4 v3 = *(const float4*)&wb[(kk + 3) * 100 + c];
                fma4(acc0, a0.x, v0); fma4(acc0, a0.y, v1); fma4(acc0, a0.z, v2); fma4(acc0, a0.w, v3);
                fma4(acc1, a1.x, v0); fma4(acc1, a1.y, v1); fma4(acc1, a1.z, v2); fma4(acc1, a1.w, v3);
            }
        }
        if (jt < 7) {
            float4* d4 = (float4*)s_w[(jt + 1) & 1];
            d4[t] = sA; d4[t + 256] = sB; d4[t + 512] = sC;
            if (t < 32) d4[t + 768] = sD;
        }
        __syncthreads();
    }

    // s_ax overlay + W_w tile0 prefetch
    float* s_ax = s_pool;
    if (t < 200) {
        float4 r;
        r.x = acc0.x * 0.2f; r.y = acc0.y * 0.2f; r.z = acc0.z * 0.2f; r.w = acc0.w * 0.2f;
        *(float4*)&s_ax[(rg * 2 + 0) * 108 + c] = r;
        r.x = acc1.x * 0.2f; r.y = acc1.y * 0.2f; r.z = acc1.z * 0.2f; r.w = acc1.w * 0.2f;
        *(float4*)&s_ax[(rg * 2 + 1) * 108 + c] = r;
    }
    const float4* ww4 = (const float4*)W_w;
    sA = ww4[t]; if (t < 244) sB = ww4[t + 256];
    {
        float4* d4 = (float4*)s_w[0];
        d4[t] = sA; if (t < 244) d4[t + 256] = sB;
    }
    __syncthreads();

    // --- GEMM2: go1 = relu(Ax @ W_w + W_b), 5 pipelined 20-row tiles
    float4 o0 = make_float4(0.f, 0.f, 0.f, 0.f);
    float4 o1 = make_float4(0.f, 0.f, 0.f, 0.f);
    for (int wt = 0; wt < 5; ++wt) {
        if (wt < 4) {
            const float4* src = ww4 + (size_t)(wt + 1) * 500;
            sA = src[t]; if (t < 244) sB = src[t + 256];
        }
        if (t < 200) {
            const float* wb = s_w[wt & 1];
            const int kb = wt * 20;
#pragma unroll 2
            for (int kk = 0; kk < 20; kk += 4) {
                float4 a0 = *(const float4*)&s_ax[(rg * 2 + 0) * 108 + kb + kk];
                float4 a1 = *(const float4*)&s_ax[(rg * 2 + 1) * 108 + kb + kk];
                float4 v0 = *(const float4*)&wb[(kk + 0) * 100 + c];
                float4 v1 = *(const float4*)&wb[(kk + 1) * 100 + c];
                float4 v2 = *(const float4*)&wb[(kk + 2) * 100 + c];
                float4 v3 = *(const float4*)&wb[(kk + 3) * 100 + c];
                fma4(o0, a0.x, v0); fma4(o0, a0.y, v1); fma4(o0, a0.z, v2); fma4(o0, a0.w, v3);
                fma4(o1, a1.x, v0); fma4(o1, a1.y, v1); fma4(o1, a1.z, v2); fma4(o1, a1.w, v3);
            }
        }
        if (wt < 4) {
            float4* d4 = (float4*)s_w[(wt + 1) & 1];
            d4[t] = sA; if (t < 244) d4[t + 256] = sB;
        }
        __syncthreads();
    }

    float* s_go = s_pool + 1728;
    if (t < 200) {
        float4 bias = *(const float4*)&W_b[c];
        o0.x = fmaxf(o0.x + bias.x, 0.f); o0.y = fmaxf(o0.y + bias.y, 0.f);
        o0.z = fmaxf(o0.z + bias.z, 0.f); o0.w = fmaxf(o0.w + bias.w, 0.f);
        o1.x = fmaxf(o1.x + bias.x, 0.f); o1.y = fmaxf(o1.y + bias.y, 0.f);
        o1.z = fmaxf(o1.z + bias.z, 0.f); o1.w = fmaxf(o1.w + bias.w, 0.f);
        *(float4*)&go1[(size_t)(b * CL + i0 + rg * 2 + 0) * CATT + c] = o0;
        *(float4*)&go1[(size_t)(b * CL + i0 + rg * 2 + 1) * CATT + c] = o1;
        *(float4*)&s_go[(rg * 2 + 0) * 104 + c] = o0;
        *(float4*)&s_go[(rg * 2 + 1) * 104 + c] = o1;
    }
    __syncthreads();

    if (t < 128) {
        int r = t >> 3, seg = t & 7;
        int e0 = seg * 13, e1 = e0 + 13 < 100 ? e0 + 13 : 100;
        float a = 0.f, c2 = 0.f;
        for (int e = e0; e < e1; ++e) {
            float v = s_go[r * 104 + e];
            a = fmaf(v, s_w1[e], a);
            c2 = fmaf(v, s_w2[e], c2);
        }
        a += __shfl_xor(a, 1); a += __shfl_xor(a, 2); a += __shfl_xor(a, 4);
        c2 += __shfl_xor(c2, 1); c2 += __shfl_xor(c2, 2); c2 += __shfl_xor(c2, 4);
        if (seg == 0) {
            s_g1row[r] = a;
            gW2S[b * CL + i0 + r] = c2;
        }
    }
    __syncthreads();

    if (t < 100) {
        float a = 0.f, s2 = 0.f;
#pragma unroll
        for (int r = 0; r < 16; ++r) {
            float v = s_go[r * 104 + t];
            a = fmaf(s_g1row[r], v, a);
            s2 += v;
        }
        atomicAdd(&t1[b * CATT + t], a);
        atomicAdd(&t2[b * CATT + t], s2);
    }
}

// ---------------------------------------------------------------------------
// k7: GCN1 with rank-1 corrections; pooled epilogue -> out1_raw atomics.
// Same pipelined staging as k45's GEMMs.
// ---------------------------------------------------------------------------
__global__ __launch_bounds__(256, 3) void k7_gcn1(
    const float* __restrict__ adjW, const float* __restrict__ go1,
    const float* __restrict__ W_w, const float* __restrict__ W_b,
    const float* __restrict__ t1, const float* __restrict__ t2,
    const float* __restrict__ gW2S, const float* __restrict__ Wx_b,
    const float* __restrict__ amask, float* __restrict__ out1_raw)
{
    __shared__ float s_pool[16 * 260];
    __shared__ float s_w[2][3200];
    const int b = blockIdx.x >> 4, ic = blockIdx.x & 15;
    const int i0 = ic * 16;
    const int t = threadIdx.x;

    {
        const float4* asrc = (const float4*)adjW + (size_t)(b * CL + i0) * 64;
#pragma unroll
        for (int m = 0; m < 4; ++m) {
            int i = t + 256 * m;
            int row = i >> 6, c4 = i & 63;
            *(float4*)&s_pool[row * 260 + c4 * 4] = asrc[i];
        }
    }
    const int cg = t % 25, rg = t / 25;
    const int c = cg * 4;
    const float4* g4 = (const float4*)go1 + (size_t)b * 6400;
    float4 sA = g4[t], sB = g4[t + 256], sC = g4[t + 512], sD;
    if (t < 32) sD = g4[t + 768];
    {
        float4* d4 = (float4*)s_w[0];
        d4[t] = sA; d4[t + 256] = sB; d4[t + 512] = sC;
        if (t < 32) d4[t + 768] = sD;
    }
    __syncthreads();

    float4 acc0 = make_float4(0.f, 0.f, 0.f, 0.f);
    float4 acc1 = make_float4(0.f, 0.f, 0.f, 0.f);
    for (int jt = 0; jt < 8; ++jt) {
        if (jt < 7) {
            const float4* src = g4 + (size_t)(jt + 1) * 800;
            sA = src[t]; sB = src[t + 256]; sC = src[t + 512];
            if (t < 32) sD = src[t + 768];
        }
        if (t < 200) {
            const float* wb = s_w[jt & 1];
#pragma unroll 2
            for (int kk = 0; kk < 32; kk += 4) {
                float4 a0 = *(const float4*)&s_pool[(rg * 2 + 0) * 260 + jt * 32 + kk];
                float4 a1 = *(const float4*)&s_pool[(rg * 2 + 1) * 260 + jt * 32 + kk];
                float4 v0 = *(const float4*)&wb[(kk + 0) * 100 + c];
                float4 v1 = *(const float4*)&wb[(kk + 1) * 100 + c];
                float4 v2 = *(const float4*)&wb[(kk + 2) * 100 + c];
                float4 v3 = *(const float4*)&wb[(kk + 3) * 100 + c];
                fma4(acc0, a0.x, v0); fma4(acc0, a0.y, v1); fma4(acc0, a0.z, v2); fma4(acc0, a0.w, v3);
                fma4(acc1, a1.x, v0); fma4(acc1, a1.y, v1); fma4(acc1, a1.z, v2); fma4(acc1, a1.w, v3);
            }
        }
        if (jt < 7) {
            float4* d4 = (float4*)s_w[(jt + 1) & 1];
            d4[t] = sA; d4[t + 256] = sB; d4[t + 512] = sC;
            if (t < 32) d4[t + 768] = sD;
        }
        __syncthreads();
    }

    float* s_ax = s_pool;
    if (t < 200) {
        float wxbs = Wx_b[0] + Wx_b[1] + Wx_b[2] + Wx_b[3] + Wx_b[4];
        float4 t1v = *(const float4*)&t1[b * CATT + c];
        float4 t2v = *(const float4*)&t2[b * CATT + c];
        float gw0 = gW2S[b * CL + i0 + rg * 2 + 0] + wxbs;
        float gw1 = gW2S[b * CL + i0 + rg * 2 + 1] + wxbs;
        float4 r;
        r.x = (acc0.x + t1v.x + gw0 * t2v.x) * 0.2f;
        r.y = (acc0.y + t1v.y + gw0 * t2v.y) * 0.2f;
        r.z = (acc0.z + t1v.z + gw0 * t2v.z) * 0.2f;
        r.w = (acc0.w + t1v.w + gw0 * t2v.w) * 0.2f;
        *(float4*)&s_ax[(rg * 2 + 0) * 108 + c] = r;
        r.x = (acc1.x + t1v.x + gw1 * t2v.x) * 0.2f;
        r.y = (acc1.y + t1v.y + gw1 * t2v.y) * 0.2f;
        r.z = (acc1.z + t1v.z + gw1 * t2v.z) * 0.2f;
        r.w = (acc1.w + t1v.w + gw1 * t2v.w) * 0.2f;
        *(float4*)&s_ax[(rg * 2 + 1) * 108 + c] = r;
    }
    const float4* ww4 = (const float4*)W_w;
    sA = ww4[t]; if (t < 244) sB = ww4[t + 256];
    {
        float4* d4 = (float4*)s_w[0];
        d4[t] = sA; if (t < 244) d4[t + 256] = sB;
    }
    __syncthreads();

    float4 o0 = make_float4(0.f, 0.f, 0.f, 0.f);
    float4 o1 = make_float4(0.f, 0.f, 0.f, 0.f);
    for (int wt = 0; wt < 5; ++wt) {
        if (wt < 4) {
            const float4* src = ww4 + (size_t)(wt + 1) * 500;
            sA = src[t]; if (t < 244) sB = src[t + 256];
        }
        if (t < 200) {
            const float* wb = s_w[wt & 1];
            const int kb = wt * 20;
#pragma unroll 2
            for (int kk = 0; kk < 20; kk += 4) {
                float4 a0 = *(const float4*)&s_ax[(rg * 2 + 0) * 108 + kb + kk];
                float4 a1 = *(const float4*)&s_ax[(rg * 2 + 1) * 108 + kb + kk];
                float4 v0 = *(const float4*)&wb[(kk + 0) * 100 + c];
                float4 v1 = *(const float4*)&wb[(kk + 1) * 100 + c];
                float4 v2 = *(const float4*)&wb[(kk + 2) * 100 + c];
                float4 v3 = *(const float4*)&wb[(kk + 3) * 100 + c];
                fma4(o0, a0.x, v0); fma4(o0, a0.y, v1); fma4(o0, a0.z, v2); fma4(o0, a0.w, v3);
                fma4(o1, a1.x, v0); fma4(o1, a1.y, v1); fma4(o1, a1.z, v2); fma4(o1, a1.w, v3);
            }
        }
        if (wt < 4) {
            float4* d4 = (float4*)s_w[(wt + 1) & 1];
            d4[t] = sA; if (t < 244) d4[t + 256] = sB;
        }
        __syncthreads();
    }

    if (t < 200) {
        float4 bias = *(const float4*)&W_b[c];
        o0.x = fmaxf(o0.x + bias.x, 0.f); o0.y = fmaxf(o0.y + bias.y, 0.f);
        o0.z = fmaxf(o0.z + bias.z, 0.f); o0.w = fmaxf(o0.w + bias.w, 0.f);
        o1.x = fmaxf(o1.x + bias.x, 0.f); o1.y = fmaxf(o1.y + bias.y, 0.f);
        o1.z = fmaxf(o1.z + bias.z, 0.f); o1.w = fmaxf(o1.w + bias.w, 0.f);
        float4 ov[2] = { o0, o1 };
#pragma unroll
        for (int q = 0; q < 2; ++q) {
            int row = b * CL + i0 + rg * 2 + q;
            float m = amask[row];
            if (m != 0.f) {
                atomicAdd(&out1_raw[b * CATT + c + 0], m * ov[q].x);
                atomicAdd(&out1_raw[b * CATT + c + 1], m * ov[q].y);
                atomicAdd(&out1_raw[b * CATT + c + 2], m * ov[q].z);
                atomicAdd(&out1_raw[b * CATT + c + 3], m * ov[q].w);
            }
        }
    }
}

// ---------------------------------------------------------------------------
__global__ __launch_bounds__(64) void k8_small(
    const float* __restrict__ out1_raw, const float* __restrict__ amask,
    const float* __restrict__ clf_w, const float* __restrict__ clf_b,
    float* __restrict__ out)
{
    const int b = blockIdx.x, t = threadIdx.x;
    float4 mv = ((const float4*)amask)[b * 64 + t];
    float wn = mv.x + mv.y + mv.z + mv.w;
#pragma unroll
    for (int o = 32; o; o >>= 1) wn += __shfl_xor(wn, o);
    if (t < 3) {
        float rwn = 1.f / wn;
        float a = clf_b[t];
        for (int d = 0; d < CATT; ++d)
            a = fmaf(out1_raw[b * CATT + d] * rwn, clf_w[d * 3 + t], a);
        out[b * 3 + t] = a;
    }
}

// ---------------------------------------------------------------------------
extern "C" void kernel_launch(void* const* d_in, const int* in_sizes, int n_in,
                              void* d_out, int out_size, void* d_ws, size_t ws_size,
                              hipStream_t stream) {
    const float* seq     = (const float*)d_in[0];
    const int*   srcm    = (const int*)d_in[1];
    const float* amask   = (const float*)d_in[2];
    const float* shortm  = (const float*)d_in[3];
    const float* ln_a    = (const float*)d_in[4];
    const float* ln_b    = (const float*)d_in[5];
    const float* Wxx_w   = (const float*)d_in[6];
    const float* Wxx_b   = (const float*)d_in[7];
    const float* q_w     = (const float*)d_in[8];
    const float* q_b     = (const float*)d_in[9];
    const float* k_w     = (const float*)d_in[10];
    const float* k_b     = (const float*)d_in[11];
    const float* dense_w = (const float*)d_in[12];
    const float* dense_b = (const float*)d_in[13];
    const float* bias_m  = (const float*)d_in[14];
    const float* W_w     = (const float*)d_in[15];
    const float* W_b     = (const float*)d_in[16];
    const float* Wx_w    = (const float*)d_in[17];
    const float* Wx_b    = (const float*)d_in[18];
    const float* clf_w   = (const float*)d_in[19];
    const float* clf_b   = (const float*)d_in[20];
    float* out = (float*)d_out;

    float* ws         = (float*)d_ws;
    float* g          = ws;
    float* qt         = g + 819200;
    float* ktb        = qt + 819200;
    float* go1        = ktb + 819200;
    float* adjW       = go1 + 819200;
    float* aspect_raw = adjW + 2097152;
    float* t1         = aspect_raw + 3200;
    float* t2         = t1 + 3200;
    float* out1_raw   = t2 + 3200;
    float* gW2S       = out1_raw + 3200;

    hipMemsetAsync(aspect_raw, 0, 4 * 3200 * sizeof(float), stream);
    hipLaunchKernelGGL(k1_fused, dim3(512), dim3(256), 0, stream, seq, ln_a, ln_b,
                       Wxx_w, Wxx_b, q_w, q_b, k_w, k_b, amask, g, qt, ktb, aspect_raw);
    hipLaunchKernelGGL(k45_attn_gcn0, dim3(512), dim3(256), 0, stream,
                       qt, ktb, aspect_raw, amask, dense_w, dense_b, bias_m, srcm,
                       shortm, Wx_w, g, W_w, W_b, adjW, go1, t1, t2, gW2S);
    hipLaunchKernelGGL(k7_gcn1, dim3(512), dim3(256), 0, stream,
                       adjW, go1, W_w, W_b, t1, t2, gW2S, Wx_b, amask, out1_raw);
    hipLaunchKernelGGL(k8_small, dim3(32), dim3(64), 0, stream,
                       out1_raw, amask, clf_w, clf_b, out);
}